// Round 6
// baseline (169.977 us; speedup 1.0000x reference)
//
#include <hip/hip_runtime.h>

#define S_DIM 512
#define B_DIM 16384
#define A_DIM 2
#define BA (B_DIM * A_DIM)   // 32768
#define HID 16
#define EMB 8
#define NPART 1000
#define TABN (NPART * HID)   // 16000
#define NG (S_DIM / 8)       // 64 groups of 8 steps

// Kernel 1: emb_proj[p][j] = b1[j] + sum_k emb_table[p][k] * W1[2+k][j]
__global__ __launch_bounds__(256) void emb_proj_kernel(
    const float* __restrict__ emb_table, const float* __restrict__ W1,
    const float* __restrict__ b1, float* __restrict__ proj) {
  int idx = blockIdx.x * 256 + threadIdx.x;
  if (idx >= TABN) return;
  int p = idx >> 4;
  int j = idx & 15;
  float acc = b1[j];
#pragma unroll
  for (int k = 0; k < EMB; ++k)
    acc = fmaf(emb_table[p * EMB + k], W1[(2 + k) * HID + j], acc);
  proj[idx] = acc;
}

// DPP quad-perm (pure VALU) for xor1/xor2 within quads.
template <int CTRL>
__device__ __forceinline__ float dppf(float x) {
  return __builtin_bit_cast(
      float, __builtin_amdgcn_update_dpp(0, __builtin_bit_cast(int, x), CTRL,
                                         0xF, 0xF, true));
}
// ds_swizzle (BitMode): src_lane = ((lane & and) | or) ^ xor
template <int OFF>
__device__ __forceinline__ int swzi(int x) {
  return __builtin_amdgcn_ds_swizzle(x, OFF);
}
template <int OFF>
__device__ __forceinline__ float swzf(float x) {
  return __builtin_bit_cast(float, swzi<OFF>(__builtin_bit_cast(int, x)));
}
#define BCOFF(S) (((S) << 5) | 0x18)  // broadcast lane S within each octet

// Kernel 2: sequential scan, 8 lanes/chain (2 hidden units each) ->
// 262144 threads = 4096 waves = 4 waves/SIMD for latency hiding.
// Groups of 8 steps: one load instr per stream per group (lane sub = step),
// ds_swizzle broadcasts hoisted to group top; table gathers 1 group ahead,
// raw streams 2 groups ahead. Rational Pade[5/4] tanh (1 rcp, no exp2).
__global__ __launch_bounds__(256, 4) void scan_kernel(
    const int* __restrict__ act, const float* __restrict__ rew,
    const int* __restrict__ pid, const float* __restrict__ W1,
    const float* __restrict__ W2, const float* __restrict__ b2,
    const float* __restrict__ proj, float* __restrict__ out) {
  int t = blockIdx.x * 256 + threadIdx.x;  // 0 .. 262143
  int chain = t >> 3;                      // 0 .. 32767 (= b*A + a)
  int sub = t & 7;                         // which 2-unit group of HID=16
  int b = chain >> 1;
  int j0 = sub << 1;

  float2 wa = *(const float2*)(W1 + j0);        // W1[0][j]
  float2 wb = *(const float2*)(W1 + HID + j0);  // W1[1][j]
  float2 w2 = *(const float2*)(W2 + j0);        // W2[j][0]
  float bb2 = b2[0];

  const float* rp = rew + chain;
  const int* ap = act + chain;
  const int* pp = pid + b;
  const float* tb = proj + j0;
  float* op = out + chain;

// one load per stream per 8-step group: lane sub covers step 8*G_+sub
#define LOAD_RAW(G_, RD, AD, PD)              \
  {                                           \
    int gg_ = (G_) < NG ? (G_) : NG - 1;      \
    size_t st_ = (size_t)(gg_ * 8 + sub);     \
    RD = rp[st_ * BA];                        \
    AD = ap[st_ * BA];                        \
    PD = pp[st_ * B_DIM];                     \
  }

// broadcast each step's pid within the octet, gather its table row pair
#define GATHER(PSRC, T0, T1, T2, T3, T4, T5, T6, T7)          \
  {                                                           \
    T0 = *(const float2*)(tb + swzi<BCOFF(0)>(PSRC) * HID);   \
    T1 = *(const float2*)(tb + swzi<BCOFF(1)>(PSRC) * HID);   \
    T2 = *(const float2*)(tb + swzi<BCOFF(2)>(PSRC) * HID);   \
    T3 = *(const float2*)(tb + swzi<BCOFF(3)>(PSRC) * HID);   \
    T4 = *(const float2*)(tb + swzi<BCOFF(4)>(PSRC) * HID);   \
    T5 = *(const float2*)(tb + swzi<BCOFF(5)>(PSRC) * HID);   \
    T6 = *(const float2*)(tb + swzi<BCOFF(6)>(PSRC) * HID);   \
    T7 = *(const float2*)(tb + swzi<BCOFF(7)>(PSRC) * HID);   \
  }

// tanh(u), u>=0: Pade[5/4] u(945+105u^2+u^4)/(945+420u^2+15u^4), clamp to 1.
// max err ~1.1e-3 (u~3.5); one v_rcp, no v_exp.
#define STEP(S_, RB_, AB_, T_)                                          \
  {                                                                     \
    float x0 = fmaf(state, wa.x, fmaf(RB_, wb.x, T_.x));                \
    float x1 = fmaf(state, wa.y, fmaf(RB_, wb.y, T_.y));                \
    x0 = fmaxf(x0, 0.f);                                                \
    x1 = fmaxf(x1, 0.f);                                                \
    float u20 = x0 * x0, u21 = x1 * x1;                                 \
    float n0 = x0 * fmaf(u20, u20 + 105.f, 945.f);                      \
    float n1 = x1 * fmaf(u21, u21 + 105.f, 945.f);                      \
    float d0 = fmaf(u20, fmaf(u20, 15.f, 420.f), 945.f);                \
    float d1 = fmaf(u21, fmaf(u21, 15.f, 420.f), 945.f);                \
    float h0 = fminf(n0 * __builtin_amdgcn_rcpf(d0), 1.f);              \
    float h1 = fminf(n1 * __builtin_amdgcn_rcpf(d1), 1.f);              \
    float ps = fmaf(h0, w2.x, h1 * w2.y);                               \
    ps += dppf<0xB1>(ps);      /* xor1 (quad) */                        \
    ps += dppf<0x4E>(ps);      /* xor2 (quad) */                        \
    ps += swzf<0x101F>(ps);    /* xor4 (cross-quad) */                  \
    float z = state + bb2 + ps;                                         \
    z = (AB_ == 1) ? z : state;                                         \
    state = __builtin_amdgcn_rcpf(                                      \
        1.f + __builtin_amdgcn_exp2f(z * -1.4426950408889634f));        \
    sv = (sub == S_) ? state : sv;                                      \
  }

  float rA, rB, rC;
  int aA, aB, aC, pA, pB, pC;
  LOAD_RAW(0, rA, aA, pA);
  LOAD_RAW(1, rB, aB, pB);

  float2 t0, t1, t2, t3, t4, t5, t6, t7;
  GATHER(pA, t0, t1, t2, t3, t4, t5, t6, t7);  // group 0 (one-time stall)

  float state = 0.f, sv = 0.f;

  for (int g = 0; g < NG; ++g) {
    LOAD_RAW(g + 2, rC, aC, pC);  // raw streams: 2-group (16-step) lead
    float2 u0, u1, u2, u3, u4, u5, u6, u7;
    GATHER(pB, u0, u1, u2, u3, u4, u5, u6, u7);  // table: 1-group lead
    // broadcast current group's r/a to all octet lanes (hoisted DS ops)
    float rb0 = swzf<BCOFF(0)>(rA), rb1 = swzf<BCOFF(1)>(rA);
    float rb2 = swzf<BCOFF(2)>(rA), rb3 = swzf<BCOFF(3)>(rA);
    float rb4 = swzf<BCOFF(4)>(rA), rb5 = swzf<BCOFF(5)>(rA);
    float rb6 = swzf<BCOFF(6)>(rA), rb7 = swzf<BCOFF(7)>(rA);
    int ab0 = swzi<BCOFF(0)>(aA), ab1 = swzi<BCOFF(1)>(aA);
    int ab2 = swzi<BCOFF(2)>(aA), ab3 = swzi<BCOFF(3)>(aA);
    int ab4 = swzi<BCOFF(4)>(aA), ab5 = swzi<BCOFF(5)>(aA);
    int ab6 = swzi<BCOFF(6)>(aA), ab7 = swzi<BCOFF(7)>(aA);

    STEP(0, rb0, ab0, t0);
    STEP(1, rb1, ab1, t1);
    STEP(2, rb2, ab2, t2);
    STEP(3, rb3, ab3, t3);
    STEP(4, rb4, ab4, t4);
    STEP(5, rb5, ab5, t5);
    STEP(6, rb6, ab6, t6);
    STEP(7, rb7, ab7, t7);

    // batched store: lane sub writes step 8g+sub (all lanes active)
    op[(size_t)(g * 8 + sub) * BA] = sv;

    // rotate pipeline
    rA = rB; aA = aB;
    rB = rC; aB = aC; pB = pC;
    t0 = u0; t1 = u1; t2 = u2; t3 = u3;
    t4 = u4; t5 = u5; t6 = u6; t7 = u7;
  }
}

extern "C" void kernel_launch(void* const* d_in, const int* in_sizes, int n_in,
                              void* d_out, int out_size, void* d_ws, size_t ws_size,
                              hipStream_t stream) {
  const int* c_Action = (const int*)d_in[0];
  const float* c_Reward = (const float*)d_in[1];
  const int* c_ParticipantID = (const int*)d_in[2];
  const float* emb_table = (const float*)d_in[3];
  const float* W1 = (const float*)d_in[4];
  const float* b1 = (const float*)d_in[5];
  const float* W2 = (const float*)d_in[6];
  const float* b2 = (const float*)d_in[7];
  float* out = (float*)d_out;
  float* proj = (float*)d_ws;  // 16000 floats = 64 KB scratch

  emb_proj_kernel<<<(TABN + 255) / 256, 256, 0, stream>>>(emb_table, W1, b1, proj);

  // 32768 chains * 8 lanes = 262144 threads; 1024 blocks -> 4 waves/SIMD
  scan_kernel<<<(BA * 8) / 256, 256, 0, stream>>>(
      c_Action, c_Reward, c_ParticipantID, W1, W2, b2, proj, out);
}